// Round 5
// baseline (498.656 us; speedup 1.0000x reference)
//
#include <hip/hip_runtime.h>
#include <hip/hip_bf16.h>

// Problem constants
#define M_ROWS  32768   // B*H*W
#define D_DIM   512     // C == latent dim
#define K_CODES 1024
#define HW      1024
#define IMG_STRIDE (D_DIM * HW)   // 524288

// d_out scratch: zh swizzled bf16 (32 MB) lives in the out_q region until the
// final gather overwrites it. idx region (last 128 KB of d_out) is real output.
// ws layout (bytes):
#define WH_OFF   0u          // 1 MB   swizzled cb-hi bf16
#define A_OFF    1048576u    // 128 KB A[i] (numpy-pairwise)
#define W_OFF    1179648u    // 4 KB   W[n]
#define PK_OFF   1183744u    // 128 KB packed candidates/flags
#define PART_OFF 1312768u    // 2.62 MB per-(row,bn) top3 partials
#define WL1_OFF  3934208u    // 128 KB worklist flag==1
#define WL2_OFF  4065280u    // 128 KB worklist flag==2
#define CNT_OFF  4196352u    // 16 B   counters
#define MK_OFF   4196368u    // 256 KB per-row 64-bit min-keys (flag==2 rows)

// 1-term bf16 error: pairwise sigma ~4.3e-5 -> 7.5 sigma = 3.2e-4, plus fp32
// reorder/grid window 1.22e-4 -> 4.4e-4; pad to 5e-4.
#define WINDOW 5.0e-4f

// ---- exact RNE fp32 ops the compiler can't contract/reassociate ----
__device__ __forceinline__ float fmul32(float a, float b) {
  float r; asm volatile("v_mul_f32 %0, %1, %2" : "=v"(r) : "v"(a), "v"(b)); return r;
}
__device__ __forceinline__ float fadd32(float a, float b) {
  float r; asm volatile("v_add_f32 %0, %1, %2" : "=v"(r) : "v"(a), "v"(b)); return r;
}
__device__ __forceinline__ float pair8(const float* r) {
  return fadd32(fadd32(fadd32(r[0], r[1]), fadd32(r[2], r[3])),
                fadd32(fadd32(r[4], r[5]), fadd32(r[6], r[7])));
}

__device__ __forceinline__ unsigned short f2bf(float x) {
  __hip_bfloat16 h = __float2bfloat16(x);
  unsigned short u; __builtin_memcpy(&u, &h, 2); return u;
}

typedef __attribute__((ext_vector_type(8))) short b8;
typedef __attribute__((ext_vector_type(4))) float f4;

__device__ __forceinline__ void gl_lds16(const void* g, void* l) {
  __builtin_amdgcn_global_load_lds(
      (const __attribute__((address_space(1))) unsigned int*)g,
      (__attribute__((address_space(3))) unsigned int*)l, 16, 0, 0);
}

// top-3 tracking (values s1<=s2<=s3; indices for first two; first-index ties)
struct T3 { float s1, s2, s3; int n1, n2; };
__device__ __forceinline__ void t3_merge(T3& a, const T3& bb) {
  T3 x = a, y = bb;
  bool bf = (y.s1 < x.s1) || (y.s1 == x.s1 && y.n1 < x.n1);
  if (bf) { T3 t = x; x = y; y = t; }
  float rs2; int rn2; float rs3;
  bool c2 = (y.s1 < x.s2) || (y.s1 == x.s2 && y.n1 < x.n2);
  if (c2) { rs2 = y.s1; rn2 = y.n1; rs3 = fminf(x.s2, y.s2); }
  else    { rs2 = x.s2; rn2 = x.n2; rs3 = fminf(x.s3, y.s1); }
  a.s1 = x.s1; a.n1 = x.n1; a.s2 = rs2; a.n2 = rn2; a.s3 = rs3;
}

// ---------------------------------------------------------------------------
// Fused: A[i] = np.sum(z^2) (exact numpy fp32 pairwise tree: 4 independent
// 128-blocks x 8 strided accumulators) + zh swizzled-bf16 emission.
// Thread (pos = t&63, bb = t>>6): 64 positions x 4 c-blocks, all 256 busy.
// zh layout: [kc 16][mb 2048][q 4][m15 16][j 8] bf16.
__global__ __launch_bounds__(256) void vq_prep(const float* __restrict__ z,
                                               float* __restrict__ A,
                                               char* __restrict__ zh_b) {
  __shared__ float zs[64 * 68];     // 64 c-rows x 64 pos (+4 pad)
  __shared__ float blks[64][4];
  const int t = threadIdx.x;
  const int pos = t & 63, bb = t >> 6;
  const int i0 = blockIdx.x * 64;
  const int b = i0 >> 10, hw0 = i0 & 1023;
  const float* zbase = z + (size_t)b * IMG_STRIDE + hw0;
  const int gpos = i0 + pos;
  const size_t mbase = (size_t)(gpos >> 4) * 1024 + (size_t)(gpos & 15) * 16;
  const int lrow = t >> 4, lcol4 = (t & 15) * 4;   // staging assignment
  float r8[8];
  alignas(16) unsigned short hs[8];
#pragma unroll
  for (int i = 0; i < 8; ++i) {     // iteration stages c = 128*g + 16*i + 0..15
    __syncthreads();
#pragma unroll
    for (int g = 0; g < 4; ++g) {
      int c = 128 * g + 16 * i + lrow;
      float4 vv = *(const float4*)(zbase + (size_t)c * HW + lcol4);
      *(float4*)(zs + (g * 16 + lrow) * 68 + lcol4) = vv;
    }
    __syncthreads();
#pragma unroll
    for (int j = 0; j < 16; ++j) {
      float v = zs[(bb * 16 + j) * 68 + pos];
      hs[j & 7] = f2bf(v);
      float pq = fmul32(v, v);
      const int k = j & 7;
      if (i == 0 && j < 8) r8[k] = pq;
      else                 r8[k] = fadd32(r8[k], pq);
      if ((j & 7) == 7) {
        int c0 = 128 * bb + 16 * i + (j - 7);
        int kc = c0 >> 5, q = (c0 >> 3) & 3;
        *(uint4*)(zh_b + (size_t)kc * 2097152 + q * 256 + mbase) = *(uint4*)hs;
      }
    }
  }
  float blkv = pair8(r8);
  __syncthreads();
  blks[pos][bb] = blkv;
  __syncthreads();
  if (t < 64)
    A[i0 + t] = fadd32(fadd32(blks[t][0], blks[t][1]),
                       fadd32(blks[t][2], blks[t][3]));
}

// Fused: W[n] = np.sum(cb^2) (exact pairwise order) + wh swizzled emission.
// wh layout: [kc 16][nb 64][q 4][n15 16][j 8] bf16. Also zeroes counters.
__global__ void vq_prepw(const float* __restrict__ cb, float* __restrict__ W,
                         char* __restrict__ wh_b, int* __restrict__ cnt) {
  if (blockIdx.x == 0 && threadIdx.x < 2) cnt[threadIdx.x] = 0;
  const int n = blockIdx.x * 256 + threadIdx.x;
  const float* wp = cb + (size_t)n * D_DIM;
  const size_t nbase = (size_t)(n >> 4) * 1024 + (size_t)(n & 15) * 16;
  float r8[8], blk[4];
  alignas(16) unsigned short hs[8];
#pragma unroll
  for (int bb = 0; bb < 4; ++bb) {
#pragma unroll
    for (int g = 0; g < 16; ++g) {
      float vv[8];
#pragma unroll
      for (int k = 0; k < 8; ++k) vv[k] = wp[bb * 128 + g * 8 + k];
#pragma unroll
      for (int k = 0; k < 8; ++k) {
        float pq = fmul32(vv[k], vv[k]);
        if (g == 0) r8[k] = pq;
        else        r8[k] = fadd32(r8[k], pq);
        hs[k] = f2bf(vv[k]);
      }
      const int kc = bb * 4 + (g >> 2), q = g & 3;
      *(uint4*)(wh_b + (size_t)kc * 65536 + q * 256 + nbase) = *(uint4*)hs;
    }
    blk[bb] = pair8(r8);
  }
  W[n] = fadd32(fadd32(blk[0], blk[1]), fadd32(blk[2], blk[3]));
}

// ---------------------------------------------------------------------------
// 1-term MFMA scoring: M ~= zh·wh (bf16, fp32 acc); s = W - 2M.
// Block tile 128 pos x 256 n; wave tile 64x128 (4x8 of 16x16x32).
__global__ __launch_bounds__(256, 2) void vq_score(
    const char* __restrict__ zh_b, const char* __restrict__ wh_b,
    const float* __restrict__ Wws, float* __restrict__ part)
{
  __shared__ __align__(16) char smem[24576];  // A 8K | B 16K
  const int tid = threadIdx.x;
  const int lane = tid & 63, wave = tid >> 6;
  const int wr = wave >> 1, wc = wave & 1;
  const int bm = blockIdx.x & 255, bn = blockIdx.x >> 8;
  const int m0 = bm * 128, n0 = bn * 256;

  f4 acc[4][8];
#pragma unroll
  for (int r = 0; r < 4; ++r)
#pragma unroll
    for (int v = 0; v < 8; ++v) acc[r][v] = (f4)(0.0f);

  for (int kc = 0; kc < 16; ++kc) {
    const char* gA = zh_b + (size_t)kc * 2097152 + (size_t)bm * 8192;
    const char* gB = wh_b + (size_t)kc * 65536 + (size_t)bn * 16384;
#pragma unroll
    for (int k = 0; k < 6; ++k) {           // 24 1KB segments, 6 per wave
      int seg = wave + 4 * k;
      const char* g; char* l;
      if (seg < 8) { g = gA + seg * 1024;        l = smem + seg * 1024; }
      else         { g = gB + (seg - 8) * 1024;  l = smem + 8192 + (seg - 8) * 1024; }
      gl_lds16(g + lane * 16, l);
    }
    __syncthreads();
    b8 bh[8];
#pragma unroll
    for (int v = 0; v < 8; ++v)
      bh[v] = *(const b8*)(smem + 8192 + ((wc * 8 + v) << 10) + (lane << 4));
#pragma unroll
    for (int r = 0; r < 4; ++r) {
      b8 ah = *(const b8*)(smem + ((wr * 4 + r) << 10) + (lane << 4));
#pragma unroll
      for (int v = 0; v < 8; ++v)
        acc[r][v] = __builtin_amdgcn_mfma_f32_16x16x32_bf16(ah, bh[v], acc[r][v], 0, 0, 0);
    }
    __syncthreads();
  }

  // epilogue: s = W - 2M; per-row top-3 across this block's 256 n
  const int l15 = lane & 15, quad = lane >> 4;
  float sW[8];
#pragma unroll
  for (int v = 0; v < 8; ++v) sW[v] = Wws[n0 + wc * 128 + v * 16 + l15];

  float* red = (float*)smem;  // [128 rows][2 wc][5]
#pragma unroll
  for (int r = 0; r < 4; ++r) {
#pragma unroll
    for (int reg = 0; reg < 4; ++reg) {
      T3 t; t.s1 = t.s2 = t.s3 = 3.4e38f; t.n1 = 0; t.n2 = 0;
#pragma unroll
      for (int v = 0; v < 8; ++v) {
        float s = fmaf(-2.f, acc[r][v][reg], sW[v]);
        int n = n0 + wc * 128 + v * 16 + l15;
        if (s < t.s1)      { t.s3 = t.s2; t.s2 = t.s1; t.n2 = t.n1; t.s1 = s; t.n1 = n; }
        else if (s < t.s2) { t.s3 = t.s2; t.s2 = s; t.n2 = n; }
        else if (s < t.s3) { t.s3 = s; }
      }
#pragma unroll
      for (int m = 1; m <= 8; m <<= 1) {   // butterfly within 16-lane quad
        T3 o;
        o.s1 = __shfl_xor(t.s1, m); o.s2 = __shfl_xor(t.s2, m); o.s3 = __shfl_xor(t.s3, m);
        o.n1 = __shfl_xor(t.n1, m); o.n2 = __shfl_xor(t.n2, m);
        t3_merge(t, o);
      }
      if (l15 == 0) {
        int row = wr * 64 + r * 16 + quad * 4 + reg;
        float* d = red + (row * 2 + wc) * 5;
        d[0] = t.s1; d[1] = t.s2; d[2] = t.s3; d[3] = (float)t.n1; d[4] = (float)t.n2;
      }
    }
  }
  __syncthreads();
  if (tid < 128) {
    const float* d0 = red + (tid * 2) * 5;
    const float* d1 = red + (tid * 2 + 1) * 5;
    T3 a; a.s1 = d0[0]; a.s2 = d0[1]; a.s3 = d0[2]; a.n1 = (int)d0[3]; a.n2 = (int)d0[4];
    T3 b; b.s1 = d1[0]; b.s2 = d1[1]; b.s3 = d1[2]; b.n1 = (int)d1[3]; b.n2 = (int)d1[4];
    t3_merge(a, b);
    float* p = part + ((size_t)(m0 + tid) * 4 + bn) * 5;
    p[0] = a.s1; p[1] = a.s2; p[2] = a.s3; p[3] = (float)a.n1; p[4] = (float)a.n2;
  }
}

// Combine 4 n-slices per row; write idx, packed candidates, worklists, keys.
__global__ void vq_comb(const float* __restrict__ part, float* __restrict__ out_idx,
                        unsigned int* __restrict__ pk, int* __restrict__ wl1,
                        int* __restrict__ wl2, int* __restrict__ cnt,
                        unsigned long long* __restrict__ minkey) {
  int row = blockIdx.x * 256 + threadIdx.x;
  const float* p = part + (size_t)row * 20;
  T3 a; a.s1 = p[0]; a.s2 = p[1]; a.s3 = p[2]; a.n1 = (int)p[3]; a.n2 = (int)p[4];
#pragma unroll
  for (int j = 1; j < 4; ++j) {
    const float* q = p + j * 5;
    T3 b; b.s1 = q[0]; b.s2 = q[1]; b.s3 = q[2]; b.n1 = (int)q[3]; b.n2 = (int)q[4];
    t3_merge(a, b);
  }
  out_idx[row] = (float)a.n1;
  unsigned int f = 0;
  if (a.s2 - a.s1 < WINDOW) f = (a.s3 - a.s1 < WINDOW) ? 2u : 1u;
  pk[row] = (unsigned int)a.n1 | ((unsigned int)a.n2 << 10) | (f << 20);
  if (f == 1u) wl1[atomicAdd(&cnt[0], 1)] = row;
  if (f == 2u) {
    minkey[row] = ~0ULL;
    wl2[atomicAdd(&cnt[1], 1)] = row;
  }
}

// fp64 top-2 recheck with reference-exact final combine; one wave per row.
__global__ __launch_bounds__(256) void vq_recheckA(
    const float* __restrict__ z, const float* __restrict__ cb,
    const float* __restrict__ Aws, const float* __restrict__ Wws,
    const unsigned int* __restrict__ pk, const int* __restrict__ wl1,
    const int* __restrict__ cnt, float* __restrict__ out_idx)
{
  const int wave = threadIdx.x >> 6, lane = threadIdx.x & 63;
  const int gw = blockIdx.x * 4 + wave;
  const int c1 = cnt[0];
  for (int i = gw; i < c1; i += 2048) {
    int row = wl1[i];
    unsigned int p = pk[row];
    int n1 = p & 1023, n2 = (p >> 10) & 1023;
    int b = row >> 10, hw = row & 1023;
    const float* zr = z + (size_t)b * IMG_STRIDE + hw;
    const float* c1p = cb + (size_t)n1 * D_DIM;
    const float* c2p = cb + (size_t)n2 * D_DIM;
    double d1 = 0.0, d2 = 0.0;
#pragma unroll
    for (int j = 0; j < 8; ++j) {
      int c = lane + 64 * j;
      double zv = (double)zr[(size_t)c * HW];
      d1 += zv * (double)c1p[c];
      d2 += zv * (double)c2p[c];
    }
#pragma unroll
    for (int off = 32; off > 0; off >>= 1) {
      d1 += __shfl_down(d1, off);
      d2 += __shfl_down(d2, off);
    }
    if (lane == 0) {
      float A_ = Aws[row];
      float e1 = fadd32(fadd32(A_, -2.f * (float)d1), Wws[n1]);
      float e2 = fadd32(fadd32(A_, -2.f * (float)d2), Wws[n2]);
      int win = (e2 < e1 || (e2 == e1 && n2 < n1)) ? n2 : n1;
      out_idx[row] = (float)win;
    }
  }
}

// Full fp64 rescan for flag==2 rows: one wave per (row, code) work item.
// Lane-parallel dot + shuffle reduce; winner via 64-bit atomicMin on
// (float_bits(e) << 10 | n) — positive e makes bits order-monotone, and the
// low bits pick the lowest index on exact ties (np.argmin semantics).
__global__ __launch_bounds__(256) void vq_recheckB(
    const float* __restrict__ z, const float* __restrict__ cb,
    const float* __restrict__ Aws, const float* __restrict__ Wws,
    const int* __restrict__ wl2, const int* __restrict__ cnt,
    unsigned long long* __restrict__ minkey)
{
  const int wave = threadIdx.x >> 6, lane = threadIdx.x & 63;
  const int gw = blockIdx.x * 4 + wave;
  const int total = cnt[1] << 10;
  for (int it = gw; it < total; it += 4096) {
    int row = wl2[it >> 10];
    int n = it & 1023;
    int b = row >> 10, hw = row & 1023;
    const float* zr = z + (size_t)b * IMG_STRIDE + hw;
    const float* cn = cb + (size_t)n * D_DIM;
    double dot = 0.0;
#pragma unroll
    for (int j = 0; j < 8; ++j) {
      int c = lane + 64 * j;
      dot += (double)zr[(size_t)c * HW] * (double)cn[c];
    }
#pragma unroll
    for (int off = 32; off > 0; off >>= 1) dot += __shfl_down(dot, off);
    if (lane == 0) {
      float e = fadd32(fadd32(Aws[row], -2.f * (float)dot), Wws[n]);
      unsigned long long key =
          ((unsigned long long)__float_as_uint(e) << 10) | (unsigned int)n;
      atomicMin(&minkey[row], key);
    }
  }
}

// Final gather: out_q rows = codebook rows (contiguous; no inverse permute).
// Also resolves flag==2 rows from minkey (and fixes out_idx for them).
// Runs last — overwrites the zh scratch living in the out_q region.
__global__ __launch_bounds__(256) void vq_gather(
    const float* __restrict__ cb, const unsigned int* __restrict__ pk,
    const unsigned long long* __restrict__ minkey,
    float* __restrict__ out_idx, float* __restrict__ out_q) {
  __shared__ int bidx[64];
  const int i0 = blockIdx.x * 64;
  if (threadIdx.x < 64) {
    int row = i0 + threadIdx.x;
    int idx;
    if (((pk[row] >> 20) & 3u) == 2u) {
      idx = (int)(minkey[row] & 1023ULL);
      out_idx[row] = (float)idx;
    } else {
      idx = (int)out_idx[row];
    }
    bidx[threadIdx.x] = idx;
  }
  __syncthreads();
  float* outp = out_q + (size_t)i0 * D_DIM;
  for (int j = 0; j < 32; ++j) {
    int f4i = j * 256 + threadIdx.x;
    int row = f4i >> 7, d4 = f4i & 127;
    float4 vv = *(const float4*)(cb + (size_t)bidx[row] * D_DIM + 4 * d4);
    *(float4*)(outp + 4 * f4i) = vv;
  }
}

extern "C" void kernel_launch(void* const* d_in, const int* in_sizes, int n_in,
                              void* d_out, int out_size, void* d_ws, size_t ws_size,
                              hipStream_t stream) {
  const float* z  = (const float*)d_in[0];
  const float* cb = (const float*)d_in[1];
  float* out_q   = (float*)d_out;
  float* out_idx = (float*)d_out + (size_t)M_ROWS * D_DIM;
  char* zh_b = (char*)d_out;                // out_q region doubles as zh scratch
  char* ws = (char*)d_ws;
  char* wh_b = ws + WH_OFF;
  float* Aws = (float*)(ws + A_OFF);
  float* Wws = (float*)(ws + W_OFF);
  unsigned int* pk = (unsigned int*)(ws + PK_OFF);
  float* part = (float*)(ws + PART_OFF);
  int* wl1 = (int*)(ws + WL1_OFF);
  int* wl2 = (int*)(ws + WL2_OFF);
  int* cnt = (int*)(ws + CNT_OFF);
  unsigned long long* minkey = (unsigned long long*)(ws + MK_OFF);

  vq_prep    <<<512, 256, 0, stream>>>(z, Aws, zh_b);
  vq_prepw   <<<4, 256, 0, stream>>>(cb, Wws, wh_b, cnt);
  vq_score   <<<1024, 256, 0, stream>>>(zh_b, wh_b, Wws, part);
  vq_comb    <<<128, 256, 0, stream>>>(part, out_idx, pk, wl1, wl2, cnt, minkey);
  vq_recheckA<<<512, 256, 0, stream>>>(z, cb, Aws, Wws, pk, wl1, cnt, out_idx);
  vq_recheckB<<<1024, 256, 0, stream>>>(z, cb, Aws, Wws, wl2, cnt, minkey);
  vq_gather  <<<512, 256, 0, stream>>>(cb, pk, minkey, out_idx, out_q);
}